// Round 8
// baseline (57.464 us; speedup 1.0000x reference)
//
#include <hip/hip_runtime.h>
#include <math.h>

// ECDA loss, 2-kernel formulation.
// KA ecda_pack: 256 blocks pack class rows into compacted bf16 matrices +
//   norms + weights + partial moments; LAST block (ticket mod 256) reduces
//   partials -> per-class scalars + 32B headers + finale (repulsion/compact).
// KB ecda_pairs: 1536 pure MFMA pair-tile blocks over packed bf16.

static constexpr int NC = 8;
static constexpr int NN = 2048;
static constexpr int DD = 256;

// workspace byte offsets
static constexpr int OFF_CNT_S = 0;         // 8 int
static constexpr int OFF_CNT_T = 64;        // 8 int
static constexpr int OFF_SW    = 128;       // 8 f32
static constexpr int OFF_SQSP  = 1024;      // 8*16 f32 partial raw-norm sums (clean)
static constexpr int OFF_SQTP  = 1536;      // 8*16 f32 (noisy)
static constexpr int OFF_HDR   = 2048;      // 24*8 f32 headers [type*8+c]: na,nb,scale,ib0..ib4
static constexpr int OFF_TICKET= 3072;      // 1 u32 (monotonic across replays; used mod 256)
static constexpr int OFF_VSP   = 4096;      // 8c*16ch*256 f32 partial moments (clean)
static constexpr int OFF_VTP   = 135168;    // same (noisy)
static constexpr int OFF_VT    = 274432;    // 8*256 f32 reduced noisy moments
static constexpr int OFF_QBFS  = 282624;    // 8*2048 f32 bf16-norms by position (clean)
static constexpr int OFF_QBFT  = 348160;    // 8*2048 f32 (noisy)
static constexpr int OFF_WTP   = 413696;    // 8*2048 f32 weights by position
static constexpr size_t OFF_PKS = 479232;   // 8*2048*256 bf16 packed clean (8 MB)
static constexpr size_t OFF_PKT = 8867840;  // packed noisy (8 MB)
// total ~17.3 MB

typedef __attribute__((ext_vector_type(8))) short bf16x8;
typedef __attribute__((ext_vector_type(4))) float f32x4;

__device__ inline float wred64(float v) {
  for (int o = 32; o > 0; o >>= 1) v += __shfl_xor(v, o, 64);
  return v;
}
__device__ inline float brs256(float v, float* sh4) {
  for (int o = 32; o > 0; o >>= 1) v += __shfl_xor(v, o, 64);
  int w = threadIdx.x >> 6, ln = threadIdx.x & 63;
  __syncthreads();
  if (ln == 0) sh4[w] = v;
  __syncthreads();
  float r = 0.f;
  if (threadIdx.x == 0) r = sh4[0] + sh4[1] + sh4[2] + sh4[3];
  return r;
}

// ---------------- KA: 256 blocks = typ(2) x class(8) x chunk(16) ----------------
__global__ __launch_bounds__(256) void ecda_pack(
    const float* __restrict__ cfeat, const float* __restrict__ nfeat,
    const int* __restrict__ clab, const int* __restrict__ nlab,
    const float* __restrict__ nmask, const float* __restrict__ nscore,
    const float* __restrict__ cw, char* __restrict__ ws,
    float* __restrict__ out) {
  __shared__ int   ls_idx[NN];
  __shared__ float ls_wt[NN];
  __shared__ int   ls_cntw[4];
  __shared__ float ls_mom[4][256];
  __shared__ float ls_sq[4];
  __shared__ float sh4[4];
  __shared__ float dcen[28];
  int tid = threadIdx.x, bx = blockIdx.x;
  int wv = tid >> 6, lane = tid & 63;
  int typ = bx >> 7, c = (bx >> 4) & 7, chunk = bx & 15;

  if (bx == 0 && tid == 0) out[0] = 0.f;

  const int* labs = typ ? nlab : clab;
  const float* feats = typ ? nfeat : cfeat;

  // pass 1: per-wave match masks over its 512 rows
  int rb = wv * 512;
  int lv[8]; float mv[8], sv[8];
#pragma unroll
  for (int it = 0; it < 8; ++it) {
    int i = rb + it * 64 + lane;
    lv[it] = labs[i];
    if (typ) { mv[it] = nmask[i]; sv[it] = nscore[i]; }
  }
  unsigned long long msks[8];
  int cntw = 0;
#pragma unroll
  for (int it = 0; it < 8; ++it) {
    bool m = (lv[it] == c) && (!typ || mv[it] > 0.5f);
    msks[it] = __ballot(m);
    cntw += __popcll(msks[it]);
  }
  if (lane == 0) ls_cntw[wv] = cntw;
  __syncthreads();
  int base = 0;
  for (int w2 = 0; w2 < wv; ++w2) base += ls_cntw[w2];
  // pass 2: write compacted list (+weights)
#pragma unroll
  for (int it = 0; it < 8; ++it) {
    bool m = (msks[it] >> lane) & 1ull;
    int pos = __popcll(msks[it] & ((1ull << lane) - 1ull));
    if (m) {
      ls_idx[base + pos] = rb + it * 64 + lane;
      ls_wt[base + pos] = typ ? sv[it] : 1.f;
    }
    base += __popcll(msks[it]);
  }
  __syncthreads();
  int count = ls_cntw[0] + ls_cntw[1] + ls_cntw[2] + ls_cntw[3];

  if (chunk == 0) {
    if (tid == 0) (typ ? (int*)(ws + OFF_CNT_T) : (int*)(ws + OFF_CNT_S))[c] = count;
    if (typ) {
      float s = 0.f;
      for (int i = tid; i < count; i += 256) s += ls_wt[i];
      s = brs256(s, sh4);
      if (tid == 0) ((float*)(ws + OFF_SW))[c] = s;
    }
  }

  // pack rows; per-wave m-stream = chunk*4 + wv (stride 64), 4-row batches
  unsigned short* pk = (unsigned short*)(ws + (typ ? OFF_PKT : OFF_PKS)) + (size_t)c * NN * DD;
  float* qarr = (float*)(ws + (typ ? OFF_QBFT : OFF_QBFS)) + c * NN;
  float* wtp  = (float*)(ws + OFF_WTP) + c * NN;
  float vax = 0.f, vay = 0.f, vaz = 0.f, vaw = 0.f, sqa = 0.f;
  int mstart = chunk * 4 + wv;
  for (int m0 = mstart; m0 < count; m0 += 256) {
    int mm[4]; bool act[4]; float4 v[4];
#pragma unroll
    for (int b = 0; b < 4; ++b) {
      int m = m0 + b * 64;
      act[b] = (m < count);
      mm[b] = act[b] ? m : m0;
    }
#pragma unroll
    for (int b = 0; b < 4; ++b) {
      int idx = ls_idx[mm[b]];
      v[b] = *(const float4*)&feats[(size_t)idx * DD + lane * 4];
    }
#pragma unroll
    for (int b = 0; b < 4; ++b) {
      float raw = wred64(v[b].x * v[b].x + v[b].y * v[b].y
                       + v[b].z * v[b].z + v[b].w * v[b].w);
      unsigned ux = __float_as_uint(v[b].x); ux = (ux + 0x7fffu + ((ux >> 16) & 1u)) & 0xffff0000u;
      unsigned uy = __float_as_uint(v[b].y); uy = (uy + 0x7fffu + ((uy >> 16) & 1u)) & 0xffff0000u;
      unsigned uz = __float_as_uint(v[b].z); uz = (uz + 0x7fffu + ((uz >> 16) & 1u)) & 0xffff0000u;
      unsigned uw = __float_as_uint(v[b].w); uw = (uw + 0x7fffu + ((uw >> 16) & 1u)) & 0xffff0000u;
      float rx = __uint_as_float(ux), ry = __uint_as_float(uy);
      float rz = __uint_as_float(uz), rw = __uint_as_float(uw);
      float rq = wred64(rx * rx + ry * ry + rz * rz + rw * rw);
      if (act[b]) {
        vax += v[b].x; vay += v[b].y; vaz += v[b].z; vaw += v[b].w;
        sqa += raw;
        ushort4 b4;
        b4.x = (unsigned short)(ux >> 16); b4.y = (unsigned short)(uy >> 16);
        b4.z = (unsigned short)(uz >> 16); b4.w = (unsigned short)(uw >> 16);
        *(ushort4*)&pk[(size_t)mm[b] * DD + lane * 4] = b4;
        if (lane == 0) {
          qarr[mm[b]] = rq;
          if (typ) wtp[mm[b]] = ls_wt[mm[b]];
        }
      }
    }
  }
  ls_mom[wv][lane * 4 + 0] = vax; ls_mom[wv][lane * 4 + 1] = vay;
  ls_mom[wv][lane * 4 + 2] = vaz; ls_mom[wv][lane * 4 + 3] = vaw;
  if (lane == 0) ls_sq[wv] = sqa;
  __syncthreads();
  float s = ls_mom[0][tid] + ls_mom[1][tid] + ls_mom[2][tid] + ls_mom[3][tid];
  float* vp = (float*)(ws + (typ ? OFF_VTP : OFF_VSP)) + (c * 16 + chunk) * 256;
  vp[tid] = s;
  if (tid == 0)
    ((float*)(ws + (typ ? OFF_SQTP : OFF_SQSP)))[c * 16 + chunk] =
        ls_sq[0] + ls_sq[1] + ls_sq[2] + ls_sq[3];

  // ---- last-block finisher (ticket mod 256: exactly one per call) ----
  __syncthreads();                          // block's stores all issued
  __shared__ unsigned s_tkt;
  __threadfence();                          // release partials (device scope)
  if (tid == 0) s_tkt = atomicAdd((unsigned*)(ws + OFF_TICKET), 1u);
  __syncthreads();
  if ((s_tkt & 255u) != 255u) return;
  __threadfence();                          // acquire: see all blocks' partials

  const float* vsp = (const float*)(ws + OFF_VSP);
  const float* vtp = (const float*)(ws + OFF_VTP);
  const float* sqsp = (const float*)(ws + OFF_SQSP);
  const float* sqtp = (const float*)(ws + OFF_SQTP);
  const int* cnt_s = (const int*)(ws + OFF_CNT_S);
  const int* cnt_t = (const int*)(ws + OFF_CNT_T);
  float* vtR = (float*)(ws + OFF_VT);
  float* hdr = (float*)(ws + OFF_HDR);
  __shared__ float sh_coef[8], sh_ccomp[8];

  // per-wave: 2 classes each
  for (int r = 0; r < 2; ++r) {
    int cc = wv * 2 + r;
    int d0 = lane * 4;
    f32x4 vsd = {0.f, 0.f, 0.f, 0.f}, vtd = {0.f, 0.f, 0.f, 0.f};
#pragma unroll
    for (int ch = 0; ch < 16; ++ch) {
      vsd += *(const f32x4*)&vsp[(cc * 16 + ch) * 256 + d0];
      vtd += *(const f32x4*)&vtp[(cc * 16 + ch) * 256 + d0];
    }
    *(f32x4*)&vtR[cc * 256 + d0] = vtd;
    float dss = wred64(vsd[0]*vsd[0] + vsd[1]*vsd[1] + vsd[2]*vsd[2] + vsd[3]*vsd[3]);
    float dtt = wred64(vtd[0]*vtd[0] + vtd[1]*vtd[1] + vtd[2]*vtd[2] + vtd[3]*vtd[3]);
    float dst = wred64(vsd[0]*vtd[0] + vsd[1]*vtd[1] + vsd[2]*vtd[2] + vsd[3]*vtd[3]);
    float sqs = wred64((lane < 16) ? sqsp[cc * 16 + lane] : 0.f);
    float sqt = wred64((lane < 16) ? sqtp[cc * 16 + lane] : 0.f);
    if (lane == 0) {
      int nsi = cnt_s[cc], nti = cnt_t[cc];
      float ns = (float)nsi, nt = (float)nti, n = ns + nt;
      float sumL2 = 2.f * ns * sqs - 2.f * dss
                  + 2.f * nt * sqt - 2.f * dtt
                  + 2.f * (nt * sqs + ns * sqt - 2.f * dst);
      float bw0 = sumL2 / fmaxf(n * n - n, 1.f) * 0.25f;  // /half, half=4
      float ib[5];
      float mul = 1.f;
      for (int k = 0; k < 5; ++k) { ib[k] = 1.f / (bw0 * mul + 1e-8f); mul *= 2.f; }
      float meanw = 0.f;
      for (int c2 = 0; c2 < NC; ++c2) meanw += cw[c2];
      meanw *= (1.f / NC);
      float attn = expf(meanw - cw[cc]);                  // LAMBDA = 1
      float coef = (nsi >= 2 && nti >= 2) ? attn : 0.f;
      float swc = ((const float*)(ws + OFF_SW))[cc];
      float scc = coef / (ns * ns + 1e-8f);
      float snn = coef / (swc * swc + 1e-8f);
      float scn = -2.f * coef / (ns * swc + 1e-8f);
      for (int ty = 0; ty < 3; ++ty) {
        float* h = hdr + (ty * 8 + cc) * 8;
        int na = (ty == 1) ? nti : nsi;
        int nb = (ty == 0) ? nsi : nti;
        h[0] = __int_as_float(na);
        h[1] = __int_as_float(nb);
        h[2] = (ty == 0) ? scc : (ty == 1) ? snn : scn;
        h[3] = ib[0]; h[4] = ib[1]; h[5] = ib[2]; h[6] = ib[3]; h[7] = ib[4];
      }
      float mx = fmaxf(nt, 1.f);
      float compact = (sqt - 2.f * dtt / mx + nt * dtt / (mx * mx)) / mx;
      sh_coef[cc] = coef;
      sh_ccomp[cc] = coef * 0.1f * compact;
    }
  }
  __syncthreads();

  // finale: repulsion + base (reads vtR written above; same block/CU/L1)
  for (int t = wv; t < 28; t += 4) {
    int a = 0, r = t;
    while (r >= 7 - a) { r -= 7 - a; ++a; }
    int b = a + 1 + r;
    float ima = 1.f / fmaxf((float)cnt_t[a], 1.f);
    float imb = 1.f / fmaxf((float)cnt_t[b], 1.f);
    float4 x = *(const float4*)&vtR[a * DD + lane * 4];
    float4 y = *(const float4*)&vtR[b * DD + lane * 4];
    float dx = x.x * ima - y.x * imb, dy = x.y * ima - y.y * imb;
    float dz = x.z * ima - y.z * imb, dw = x.w * ima - y.w * imb;
    float ssum = wred64(dx * dx + dy * dy + dz * dz + dw * dw);
    if (lane == 0) dcen[t] = sqrtf(fmaxf(ssum, 1e-12f));
  }
  __syncthreads();
  if (tid == 0) {
    int nvalid = 0;
    for (int c2 = 0; c2 < NC; ++c2) nvalid += (cnt_t[c2] > 0);
    float sumD = 0.f; int np = 0; int p = 0;
    for (int a = 0; a < NC; ++a)
      for (int b = a + 1; b < NC; ++b) {
        if (cnt_t[a] > 0 && cnt_t[b] > 0) { sumD += dcen[p]; ++np; }
        ++p;
      }
    float repl = (nvalid > 1) ? (-sumD / fmaxf((float)np, 1.f)) : 0.f;
    float base2 = 0.f, csum = 0.f;
    for (int c2 = 0; c2 < NC; ++c2) { base2 += sh_ccomp[c2]; csum += sh_coef[c2]; }
    base2 += 0.01f * repl * csum;
    atomicAdd(out, base2);
  }
}

// ---------------- KB: 1536 tile blocks ----------------
__global__ __launch_bounds__(256) void ecda_pairs(
    char* __restrict__ ws, float* __restrict__ out) {
  __shared__ float shred[4];
  int tid = threadIdx.x, bx = blockIdx.x;
  int wv = tid >> 6, lane = tid & 63;

  int type  = bx >> 9;
  int c     = (bx >> 6) & 7;
  int rtile = (bx >> 3) & 7;
  int ctile = bx & 7;
  if (type <= 1 && ctile < rtile) return;  // symmetric: upper only (no loads)

  const f32x4* H = (const f32x4*)((const char*)ws + OFF_HDR) + (type * 8 + c) * 2;
  f32x4 h0 = H[0];
  int na = __float_as_int(h0[0]);
  int nb = __float_as_int(h0[1]);
  float scale = h0[2];
  int rbase = rtile * 32, cbase = ctile * 32;
  if (scale == 0.f || rbase >= na || cbase >= nb) return;
  f32x4 h1 = H[1];
  float ib0 = h0[3], ib1 = h1[0], ib2 = h1[1], ib3 = h1[2], ib4 = h1[3];
  float factor = (type <= 1 && ctile > rtile) ? 2.f : 1.f;

  const unsigned short* pkS = (const unsigned short*)(ws + OFF_PKS) + (size_t)c * NN * DD;
  const unsigned short* pkT = (const unsigned short*)(ws + OFF_PKT) + (size_t)c * NN * DD;
  const float* qbS = (const float*)(ws + OFF_QBFS) + c * NN;
  const float* qbT = (const float*)(ws + OFF_QBFT) + c * NN;
  const float* wtp = (const float*)(ws + OFF_WTP) + c * NN;
  const unsigned short* pkA = (type == 1) ? pkT : pkS;
  const unsigned short* pkB = (type == 0) ? pkS : pkT;
  const float* qaB = (type == 1) ? qbT : qbS;
  const float* qbB = (type == 0) ? qbS : qbT;

  int sr = (wv >> 1) * 16, sc2 = (wv & 1) * 16;
  int posA = rbase + sr + (lane & 15);
  int posB = cbase + sc2 + (lane & 15);
  int pAc = posA < na ? posA : (na - 1);
  int pBc = posB < nb ? posB : (nb - 1);
  const unsigned short* rowA = pkA + (size_t)pAc * DD + (lane >> 4) * 8;
  const unsigned short* rowB = pkB + (size_t)pBc * DD + (lane >> 4) * 8;

  f32x4 acc = {0.f, 0.f, 0.f, 0.f};
#pragma unroll
  for (int ks = 0; ks < 8; ++ks) {
    bf16x8 af = *(const bf16x8*)(rowA + ks * 32);
    bf16x8 bf = *(const bf16x8*)(rowB + ks * 32);
    acc = __builtin_amdgcn_mfma_f32_16x16x32_bf16(af, bf, acc, 0, 0, 0);
  }

  // epilogue: lane holds D[row][col], col = cbase+sc2+(lane&15), row = rowbase+r
  bool jval = (posB < nb);
  float knj = qbB[pBc];
  float wj = (type == 0) ? 1.f : wtp[pBc];
  int rowbase = rbase + sr + ((lane >> 4) << 2);          // multiple of 4
  f32x4 qA4 = *(const f32x4*)&qaB[rowbase];               // poison past count is gated
  f32x4 wA4 = {1.f, 1.f, 1.f, 1.f};
  if (type == 1) wA4 = *(const f32x4*)&wtp[rowbase];
  float partial = 0.f;
#pragma unroll
  for (int r = 0; r < 4; ++r) {
    int ip = rowbase + r;
    bool val = jval && (ip < na);
    float d2 = fmaxf(qA4[r] + knj - 2.f * acc[r], 0.f);
    float e = __expf(-d2 * ib0) + __expf(-d2 * ib1) + __expf(-d2 * ib2)
            + __expf(-d2 * ib3) + __expf(-d2 * ib4);
    float wgt = (type == 1) ? wA4[r] * wj : wj;
    partial += val ? wgt * e : 0.f;
  }
  partial = wred64(partial);
  if (lane == 0) shred[wv] = partial;
  __syncthreads();
  if (tid == 0) {
    float tot = shred[0] + shred[1] + shred[2] + shred[3];
    atomicAdd(out, scale * factor * tot);
  }
}

extern "C" void kernel_launch(void* const* d_in, const int* in_sizes, int n_in,
                              void* d_out, int out_size, void* d_ws, size_t ws_size,
                              hipStream_t stream) {
  const float* cfeat  = (const float*)d_in[0];
  const float* nfeat  = (const float*)d_in[1];
  const int*   clab   = (const int*)d_in[2];
  const int*   nlab   = (const int*)d_in[3];
  const float* nmask  = (const float*)d_in[4];
  const float* nscore = (const float*)d_in[5];
  const float* cw     = (const float*)d_in[6];
  float* out = (float*)d_out;
  char* ws = (char*)d_ws;

  ecda_pack<<<256, 256, 0, stream>>>(cfeat, nfeat, clab, nlab, nmask, nscore,
                                     cw, ws, out);
  ecda_pairs<<<1536, 256, 0, stream>>>(ws, out);
}

// Round 9
// 33.295 us; speedup vs baseline: 1.7259x; 1.7259x over previous
//
#include <hip/hip_runtime.h>
#include <math.h>

// ECDA loss, 2-kernel formulation, fence-free.
// KA ecda_pack: 256 blocks pack class rows into compacted bf16 matrices +
//   per-position norms + weights + chunk-partial moments/norm-sums.
// KB ecda_pairs: 1536 MFMA pair-tile blocks, each computing its class's
//   scalars REDUNDANTLY from the partials (reads only; kernel boundary
//   provides visibility — no grid.sync, no threadfence, no ticket);
//   block 1536 = finale (repulsion + compact + base).

static constexpr int NC = 8;
static constexpr int NN = 2048;
static constexpr int DD = 256;

// workspace byte offsets
static constexpr int OFF_CNT_S = 0;         // 8 int
static constexpr int OFF_CNT_T = 64;        // 8 int
static constexpr int OFF_SW    = 128;       // 8 f32
static constexpr int OFF_SQSP  = 1024;      // 8*16 f32 partial raw-norm sums (clean)
static constexpr int OFF_SQTP  = 1536;      // 8*16 f32 (noisy)
static constexpr int OFF_VSP   = 4096;      // 8c*16ch*256 f32 partial moments (clean)
static constexpr int OFF_VTP   = 135168;    // same (noisy)
static constexpr int OFF_QBFS  = 282624;    // 8*2048 f32 bf16-norms by position (clean)
static constexpr int OFF_QBFT  = 348160;    // 8*2048 f32 (noisy)
static constexpr int OFF_WTP   = 413696;    // 8*2048 f32 weights by position
static constexpr size_t OFF_PKS = 479232;   // 8*2048*256 bf16 packed clean (8 MB)
static constexpr size_t OFF_PKT = 8867840;  // packed noisy (8 MB)
// total ~17.3 MB

typedef __attribute__((ext_vector_type(8))) short bf16x8;
typedef __attribute__((ext_vector_type(4))) float f32x4;

__device__ inline float wred64(float v) {
  for (int o = 32; o > 0; o >>= 1) v += __shfl_xor(v, o, 64);
  return v;
}
__device__ inline float brs256(float v, float* sh4) {
  for (int o = 32; o > 0; o >>= 1) v += __shfl_xor(v, o, 64);
  int w = threadIdx.x >> 6, ln = threadIdx.x & 63;
  __syncthreads();
  if (ln == 0) sh4[w] = v;
  __syncthreads();
  float r = 0.f;
  if (threadIdx.x == 0) r = sh4[0] + sh4[1] + sh4[2] + sh4[3];
  return r;
}

// ---------------- KA: 256 blocks = typ(2) x class(8) x chunk(16) ----------------
__global__ __launch_bounds__(256) void ecda_pack(
    const float* __restrict__ cfeat, const float* __restrict__ nfeat,
    const int* __restrict__ clab, const int* __restrict__ nlab,
    const float* __restrict__ nmask, const float* __restrict__ nscore,
    char* __restrict__ ws, float* __restrict__ out) {
  __shared__ int   ls_idx[NN];
  __shared__ float ls_wt[NN];
  __shared__ int   ls_cntw[4];
  __shared__ float ls_mom[4][256];
  __shared__ float ls_sq[4];
  __shared__ float sh4[4];
  int tid = threadIdx.x, bx = blockIdx.x;
  int wv = tid >> 6, lane = tid & 63;
  int typ = bx >> 7, c = (bx >> 4) & 7, chunk = bx & 15;

  if (bx == 0 && tid == 0) out[0] = 0.f;

  const int* labs = typ ? nlab : clab;
  const float* feats = typ ? nfeat : cfeat;

  // pass 1: per-wave match masks over its 512 rows
  int rb = wv * 512;
  int lv[8]; float mv[8], sv[8];
#pragma unroll
  for (int it = 0; it < 8; ++it) {
    int i = rb + it * 64 + lane;
    lv[it] = labs[i];
    if (typ) { mv[it] = nmask[i]; sv[it] = nscore[i]; }
  }
  unsigned long long msks[8];
  int cntw = 0;
#pragma unroll
  for (int it = 0; it < 8; ++it) {
    bool m = (lv[it] == c) && (!typ || mv[it] > 0.5f);
    msks[it] = __ballot(m);
    cntw += __popcll(msks[it]);
  }
  if (lane == 0) ls_cntw[wv] = cntw;
  __syncthreads();
  int base = 0;
  for (int w2 = 0; w2 < wv; ++w2) base += ls_cntw[w2];
  // pass 2: write compacted list (+weights)
#pragma unroll
  for (int it = 0; it < 8; ++it) {
    bool m = (msks[it] >> lane) & 1ull;
    int pos = __popcll(msks[it] & ((1ull << lane) - 1ull));
    if (m) {
      ls_idx[base + pos] = rb + it * 64 + lane;
      ls_wt[base + pos] = typ ? sv[it] : 1.f;
    }
    base += __popcll(msks[it]);
  }
  __syncthreads();
  int count = ls_cntw[0] + ls_cntw[1] + ls_cntw[2] + ls_cntw[3];

  if (chunk == 0) {
    if (tid == 0) (typ ? (int*)(ws + OFF_CNT_T) : (int*)(ws + OFF_CNT_S))[c] = count;
    if (typ) {
      float s = 0.f;
      for (int i = tid; i < count; i += 256) s += ls_wt[i];
      s = brs256(s, sh4);
      if (tid == 0) ((float*)(ws + OFF_SW))[c] = s;
    }
  }

  // pack rows; per-wave m-stream = chunk*4 + wv (stride 64), 4-row batches
  unsigned short* pk = (unsigned short*)(ws + (typ ? OFF_PKT : OFF_PKS)) + (size_t)c * NN * DD;
  float* qarr = (float*)(ws + (typ ? OFF_QBFT : OFF_QBFS)) + c * NN;
  float* wtp  = (float*)(ws + OFF_WTP) + c * NN;
  float vax = 0.f, vay = 0.f, vaz = 0.f, vaw = 0.f, sqa = 0.f;
  int mstart = chunk * 4 + wv;
  for (int m0 = mstart; m0 < count; m0 += 256) {
    int mm[4]; bool act[4]; float4 v[4];
#pragma unroll
    for (int b = 0; b < 4; ++b) {
      int m = m0 + b * 64;
      act[b] = (m < count);
      mm[b] = act[b] ? m : m0;
    }
#pragma unroll
    for (int b = 0; b < 4; ++b) {
      int idx = ls_idx[mm[b]];
      v[b] = *(const float4*)&feats[(size_t)idx * DD + lane * 4];
    }
#pragma unroll
    for (int b = 0; b < 4; ++b) {
      float raw = wred64(v[b].x * v[b].x + v[b].y * v[b].y
                       + v[b].z * v[b].z + v[b].w * v[b].w);
      unsigned ux = __float_as_uint(v[b].x); ux = (ux + 0x7fffu + ((ux >> 16) & 1u)) & 0xffff0000u;
      unsigned uy = __float_as_uint(v[b].y); uy = (uy + 0x7fffu + ((uy >> 16) & 1u)) & 0xffff0000u;
      unsigned uz = __float_as_uint(v[b].z); uz = (uz + 0x7fffu + ((uz >> 16) & 1u)) & 0xffff0000u;
      unsigned uw = __float_as_uint(v[b].w); uw = (uw + 0x7fffu + ((uw >> 16) & 1u)) & 0xffff0000u;
      float rx = __uint_as_float(ux), ry = __uint_as_float(uy);
      float rz = __uint_as_float(uz), rw = __uint_as_float(uw);
      float rq = wred64(rx * rx + ry * ry + rz * rz + rw * rw);
      if (act[b]) {
        vax += v[b].x; vay += v[b].y; vaz += v[b].z; vaw += v[b].w;
        sqa += raw;
        ushort4 b4;
        b4.x = (unsigned short)(ux >> 16); b4.y = (unsigned short)(uy >> 16);
        b4.z = (unsigned short)(uz >> 16); b4.w = (unsigned short)(uw >> 16);
        *(ushort4*)&pk[(size_t)mm[b] * DD + lane * 4] = b4;
        if (lane == 0) {
          qarr[mm[b]] = rq;
          if (typ) wtp[mm[b]] = ls_wt[mm[b]];
        }
      }
    }
  }
  ls_mom[wv][lane * 4 + 0] = vax; ls_mom[wv][lane * 4 + 1] = vay;
  ls_mom[wv][lane * 4 + 2] = vaz; ls_mom[wv][lane * 4 + 3] = vaw;
  if (lane == 0) ls_sq[wv] = sqa;
  __syncthreads();
  float s = ls_mom[0][tid] + ls_mom[1][tid] + ls_mom[2][tid] + ls_mom[3][tid];
  float* vp = (float*)(ws + (typ ? OFF_VTP : OFF_VSP)) + (c * 16 + chunk) * 256;
  vp[tid] = s;
  if (tid == 0)
    ((float*)(ws + (typ ? OFF_SQTP : OFF_SQSP)))[c * 16 + chunk] =
        ls_sq[0] + ls_sq[1] + ls_sq[2] + ls_sq[3];
}

// ---------------- KB: 1537 blocks (1536 tiles + finale) ----------------
__global__ __launch_bounds__(256) void ecda_pairs(
    const float* __restrict__ cw, char* __restrict__ ws,
    float* __restrict__ out) {
  __shared__ float shred[4];
  __shared__ float sh4[4];
  __shared__ float shb[8];      // 0:dss 1:dtt 2:dst 3:sqs 4:sqt
  __shared__ float shs[6];      // scale*factor, ib0..ib4
  __shared__ float sh_vt[8][256];
  __shared__ float sh_coef[8], sh_ccomp[8];
  __shared__ float dcen[28];
  int tid = threadIdx.x, bx = blockIdx.x;
  int wv = tid >> 6, lane = tid & 63;
  const int* cnt_s = (const int*)(ws + OFF_CNT_S);
  const int* cnt_t = (const int*)(ws + OFF_CNT_T);
  const float* vsp = (const float*)(ws + OFF_VSP);
  const float* vtp = (const float*)(ws + OFF_VTP);
  const float* sqsp = (const float*)(ws + OFF_SQSP);
  const float* sqtp = (const float*)(ws + OFF_SQTP);

  if (bx == 1536) {                        // finale: repulsion + compact + base
    float meanw = 0.f;
    for (int c2 = 0; c2 < NC; ++c2) meanw += cw[c2];
    meanw *= (1.f / NC);
    for (int cc = wv; cc < 8; cc += 4) {   // each wave handles 2 classes
      f32x4 vtd = {0.f, 0.f, 0.f, 0.f};
#pragma unroll
      for (int ch = 0; ch < 16; ++ch)
        vtd += *(const f32x4*)&vtp[(cc * 16 + ch) * 256 + lane * 4];
      *(f32x4*)&sh_vt[cc][lane * 4] = vtd;
      float dtt = wred64(vtd[0]*vtd[0] + vtd[1]*vtd[1] + vtd[2]*vtd[2] + vtd[3]*vtd[3]);
      float sqt = wred64((lane < 16) ? sqtp[cc * 16 + lane] : 0.f);
      if (lane == 0) {
        int nsi = cnt_s[cc], nti = cnt_t[cc];
        float nt = (float)nti;
        float coef = (nsi >= 2 && nti >= 2) ? expf(meanw - cw[cc]) : 0.f;
        float mx = fmaxf(nt, 1.f);
        float compact = (sqt - 2.f * dtt / mx + nt * dtt / (mx * mx)) / mx;
        sh_coef[cc] = coef;
        sh_ccomp[cc] = coef * 0.1f * compact;
      }
    }
    __syncthreads();
    for (int t = wv; t < 28; t += 4) {
      int a = 0, r = t;
      while (r >= 7 - a) { r -= 7 - a; ++a; }
      int b = a + 1 + r;
      float ima = 1.f / fmaxf((float)cnt_t[a], 1.f);
      float imb = 1.f / fmaxf((float)cnt_t[b], 1.f);
      float4 x = *(const float4*)&sh_vt[a][lane * 4];
      float4 y = *(const float4*)&sh_vt[b][lane * 4];
      float dx = x.x * ima - y.x * imb, dy = x.y * ima - y.y * imb;
      float dz = x.z * ima - y.z * imb, dw = x.w * ima - y.w * imb;
      float ssum = wred64(dx * dx + dy * dy + dz * dz + dw * dw);
      if (lane == 0) dcen[t] = sqrtf(fmaxf(ssum, 1e-12f));
    }
    __syncthreads();
    if (tid == 0) {
      int nvalid = 0;
      for (int c2 = 0; c2 < NC; ++c2) nvalid += (cnt_t[c2] > 0);
      float sumD = 0.f; int np = 0; int p = 0;
      for (int a = 0; a < NC; ++a)
        for (int b = a + 1; b < NC; ++b) {
          if (cnt_t[a] > 0 && cnt_t[b] > 0) { sumD += dcen[p]; ++np; }
          ++p;
        }
      float repl = (nvalid > 1) ? (-sumD / fmaxf((float)np, 1.f)) : 0.f;
      float base2 = 0.f, csum = 0.f;
      for (int c2 = 0; c2 < NC; ++c2) { base2 += sh_ccomp[c2]; csum += sh_coef[c2]; }
      base2 += 0.01f * repl * csum;
      atomicAdd(out, base2);
    }
    return;
  }

  // -------- tile block --------
  int type  = bx >> 9;
  int c     = (bx >> 6) & 7;
  int rtile = (bx >> 3) & 7;
  int ctile = bx & 7;
  if (type <= 1 && ctile < rtile) return;  // symmetric: upper only (no loads)

  int nsc = cnt_s[c], ntc = cnt_t[c];
  if (nsc < 2 || ntc < 2) return;          // gated class (coef == 0)
  int na = (type == 1) ? ntc : nsc;
  int nb = (type == 0) ? nsc : ntc;
  int rbase = rtile * 32, cbase = ctile * 32;
  if (rbase >= na || cbase >= nb) return;
  float factor = (type <= 1 && ctile > rtile) ? 2.f : 1.f;

  // redundant per-class scalar prologue from chunk partials (reads only)
  {
    float vsd = 0.f, vtd = 0.f;
#pragma unroll
    for (int ch = 0; ch < 16; ++ch) {
      vsd += vsp[(c * 16 + ch) * 256 + tid];
      vtd += vtp[(c * 16 + ch) * 256 + tid];
    }
    if (wv == 2) {
      float s = wred64((lane < 16) ? sqsp[c * 16 + lane] : 0.f);
      if (lane == 0) shb[3] = s;
    }
    if (wv == 3) {
      float s = wred64((lane < 16) ? sqtp[c * 16 + lane] : 0.f);
      if (lane == 0) shb[4] = s;
    }
    float r1 = brs256(vsd * vsd, sh4); if (tid == 0) shb[0] = r1;
    float r2 = brs256(vtd * vtd, sh4); if (tid == 0) shb[1] = r2;
    float r3 = brs256(vsd * vtd, sh4); if (tid == 0) shb[2] = r3;
    __syncthreads();
    if (tid == 0) {
      float ns = (float)nsc, nt = (float)ntc, n = ns + nt;
      float sumL2 = 2.f * ns * shb[3] - 2.f * shb[0]
                  + 2.f * nt * shb[4] - 2.f * shb[1]
                  + 2.f * (nt * shb[3] + ns * shb[4] - 2.f * shb[2]);
      float bw0 = sumL2 / fmaxf(n * n - n, 1.f) * 0.25f;  // /half, half=4
      float mul = 1.f;
      for (int k = 0; k < 5; ++k) { shs[1 + k] = 1.f / (bw0 * mul + 1e-8f); mul *= 2.f; }
      float meanw = 0.f;
      for (int c2 = 0; c2 < NC; ++c2) meanw += cw[c2];
      meanw *= (1.f / NC);
      float attn = expf(meanw - cw[c]);                    // LAMBDA = 1
      float swc = ((const float*)(ws + OFF_SW))[c];
      float scale = (type == 0) ? attn / (ns * ns + 1e-8f)
                  : (type == 1) ? attn / (swc * swc + 1e-8f)
                                : -2.f * attn / (ns * swc + 1e-8f);
      shs[0] = scale * factor;
    }
    __syncthreads();
  }
  float ib0 = shs[1], ib1 = shs[2], ib2 = shs[3], ib3 = shs[4], ib4 = shs[5];

  const unsigned short* pkS = (const unsigned short*)(ws + OFF_PKS) + (size_t)c * NN * DD;
  const unsigned short* pkT = (const unsigned short*)(ws + OFF_PKT) + (size_t)c * NN * DD;
  const float* qbS = (const float*)(ws + OFF_QBFS) + c * NN;
  const float* qbT = (const float*)(ws + OFF_QBFT) + c * NN;
  const float* wtp = (const float*)(ws + OFF_WTP) + c * NN;
  const unsigned short* pkA = (type == 1) ? pkT : pkS;
  const unsigned short* pkB = (type == 0) ? pkS : pkT;
  const float* qaB = (type == 1) ? qbT : qbS;
  const float* qbB = (type == 0) ? qbS : qbT;

  int sr = (wv >> 1) * 16, sc2 = (wv & 1) * 16;
  int posA = rbase + sr + (lane & 15);
  int posB = cbase + sc2 + (lane & 15);
  int pAc = posA < na ? posA : (na - 1);
  int pBc = posB < nb ? posB : (nb - 1);
  const unsigned short* rowA = pkA + (size_t)pAc * DD + (lane >> 4) * 8;
  const unsigned short* rowB = pkB + (size_t)pBc * DD + (lane >> 4) * 8;

  f32x4 acc = {0.f, 0.f, 0.f, 0.f};
#pragma unroll
  for (int ks = 0; ks < 8; ++ks) {
    bf16x8 af = *(const bf16x8*)(rowA + ks * 32);
    bf16x8 bf = *(const bf16x8*)(rowB + ks * 32);
    acc = __builtin_amdgcn_mfma_f32_16x16x32_bf16(af, bf, acc, 0, 0, 0);
  }

  // epilogue: lane holds D[row][col], col = cbase+sc2+(lane&15), row = rowbase+r
  bool jval = (posB < nb);
  float knj = qbB[pBc];
  float wj = (type == 0) ? 1.f : wtp[pBc];
  int rowbase = rbase + sr + ((lane >> 4) << 2);          // multiple of 4
  f32x4 qA4 = *(const f32x4*)&qaB[rowbase];               // poison past count is gated
  f32x4 wA4 = {1.f, 1.f, 1.f, 1.f};
  if (type == 1) wA4 = *(const f32x4*)&wtp[rowbase];
  float partial = 0.f;
#pragma unroll
  for (int r = 0; r < 4; ++r) {
    int ip = rowbase + r;
    bool val = jval && (ip < na);
    float d2 = fmaxf(qA4[r] + knj - 2.f * acc[r], 0.f);
    float e = __expf(-d2 * ib0) + __expf(-d2 * ib1) + __expf(-d2 * ib2)
            + __expf(-d2 * ib3) + __expf(-d2 * ib4);
    float wgt = (type == 1) ? wA4[r] * wj : wj;
    partial += val ? wgt * e : 0.f;
  }
  partial = wred64(partial);
  if (lane == 0) shred[wv] = partial;
  __syncthreads();
  if (tid == 0) {
    float tot = shred[0] + shred[1] + shred[2] + shred[3];
    atomicAdd(out, shs[0] * tot);
  }
}

extern "C" void kernel_launch(void* const* d_in, const int* in_sizes, int n_in,
                              void* d_out, int out_size, void* d_ws, size_t ws_size,
                              hipStream_t stream) {
  const float* cfeat  = (const float*)d_in[0];
  const float* nfeat  = (const float*)d_in[1];
  const int*   clab   = (const int*)d_in[2];
  const int*   nlab   = (const int*)d_in[3];
  const float* nmask  = (const float*)d_in[4];
  const float* nscore = (const float*)d_in[5];
  const float* cw     = (const float*)d_in[6];
  float* out = (float*)d_out;
  char* ws = (char*)d_ws;

  ecda_pack<<<256, 256, 0, stream>>>(cfeat, nfeat, clab, nlab, nmask, nscore,
                                     ws, out);
  ecda_pairs<<<1537, 256, 0, stream>>>(cw, ws, out);
}

// Round 10
// 32.741 us; speedup vs baseline: 1.7551x; 1.0169x over previous
//
#include <hip/hip_runtime.h>
#include <math.h>

// ECDA loss, 2-kernel formulation, fence-free, stripe-merged tiles.
// KA ecda_pack: 256 blocks pack class rows into compacted bf16 matrices +
//   per-position norms + weights + chunk-partial moments/norm-sums.
// KB ecda_pairs: 192 row-stripe MFMA blocks (prologue + A-frags once per
//   block, loop over column tiles, ONE atomicAdd per block) + finale block.

static constexpr int NC = 8;
static constexpr int NN = 2048;
static constexpr int DD = 256;

// workspace byte offsets
static constexpr int OFF_CNT_S = 0;         // 8 int
static constexpr int OFF_CNT_T = 64;        // 8 int
static constexpr int OFF_SW    = 128;       // 8 f32
static constexpr int OFF_SQSP  = 1024;      // 8*16 f32 partial raw-norm sums (clean)
static constexpr int OFF_SQTP  = 1536;      // 8*16 f32 (noisy)
static constexpr int OFF_VSP   = 4096;      // 8c*16ch*256 f32 partial moments (clean)
static constexpr int OFF_VTP   = 135168;    // same (noisy)
static constexpr int OFF_QBFS  = 282624;    // 8*2048 f32 bf16-norms by position (clean)
static constexpr int OFF_QBFT  = 348160;    // 8*2048 f32 (noisy)
static constexpr int OFF_WTP   = 413696;    // 8*2048 f32 weights by position
static constexpr size_t OFF_PKS = 479232;   // 8*2048*256 bf16 packed clean (8 MB)
static constexpr size_t OFF_PKT = 8867840;  // packed noisy (8 MB)
// total ~17.3 MB

typedef __attribute__((ext_vector_type(8))) short bf16x8;
typedef __attribute__((ext_vector_type(4))) float f32x4;

__device__ inline float wred64(float v) {
  for (int o = 32; o > 0; o >>= 1) v += __shfl_xor(v, o, 64);
  return v;
}
__device__ inline float brs256(float v, float* sh4) {
  for (int o = 32; o > 0; o >>= 1) v += __shfl_xor(v, o, 64);
  int w = threadIdx.x >> 6, ln = threadIdx.x & 63;
  __syncthreads();
  if (ln == 0) sh4[w] = v;
  __syncthreads();
  float r = 0.f;
  if (threadIdx.x == 0) r = sh4[0] + sh4[1] + sh4[2] + sh4[3];
  return r;
}

// ---------------- KA: 256 blocks = typ(2) x class(8) x chunk(16) ----------------
__global__ __launch_bounds__(256) void ecda_pack(
    const float* __restrict__ cfeat, const float* __restrict__ nfeat,
    const int* __restrict__ clab, const int* __restrict__ nlab,
    const float* __restrict__ nmask, const float* __restrict__ nscore,
    char* __restrict__ ws, float* __restrict__ out) {
  __shared__ int   ls_idx[NN];
  __shared__ float ls_wt[NN];
  __shared__ int   ls_cntw[4];
  __shared__ float ls_mom[4][256];
  __shared__ float ls_sq[4];
  __shared__ float sh4[4];
  int tid = threadIdx.x, bx = blockIdx.x;
  int wv = tid >> 6, lane = tid & 63;
  int typ = bx >> 7, c = (bx >> 4) & 7, chunk = bx & 15;

  if (bx == 0 && tid == 0) out[0] = 0.f;

  const int* labs = typ ? nlab : clab;
  const float* feats = typ ? nfeat : cfeat;

  // pass 1: per-wave match masks over its 512 rows
  int rb = wv * 512;
  int lv[8]; float mv[8], sv[8];
#pragma unroll
  for (int it = 0; it < 8; ++it) {
    int i = rb + it * 64 + lane;
    lv[it] = labs[i];
    if (typ) { mv[it] = nmask[i]; sv[it] = nscore[i]; }
  }
  unsigned long long msks[8];
  int cntw = 0;
#pragma unroll
  for (int it = 0; it < 8; ++it) {
    bool m = (lv[it] == c) && (!typ || mv[it] > 0.5f);
    msks[it] = __ballot(m);
    cntw += __popcll(msks[it]);
  }
  if (lane == 0) ls_cntw[wv] = cntw;
  __syncthreads();
  int base = 0;
  for (int w2 = 0; w2 < wv; ++w2) base += ls_cntw[w2];
  // pass 2: write compacted list (+weights)
#pragma unroll
  for (int it = 0; it < 8; ++it) {
    bool m = (msks[it] >> lane) & 1ull;
    int pos = __popcll(msks[it] & ((1ull << lane) - 1ull));
    if (m) {
      ls_idx[base + pos] = rb + it * 64 + lane;
      ls_wt[base + pos] = typ ? sv[it] : 1.f;
    }
    base += __popcll(msks[it]);
  }
  __syncthreads();
  int count = ls_cntw[0] + ls_cntw[1] + ls_cntw[2] + ls_cntw[3];

  if (chunk == 0) {
    if (tid == 0) (typ ? (int*)(ws + OFF_CNT_T) : (int*)(ws + OFF_CNT_S))[c] = count;
    if (typ) {
      float s = 0.f;
      for (int i = tid; i < count; i += 256) s += ls_wt[i];
      s = brs256(s, sh4);
      if (tid == 0) ((float*)(ws + OFF_SW))[c] = s;
    }
  }

  // pack rows; per-wave m-stream = chunk*4 + wv (stride 256), 4-row batches
  unsigned short* pk = (unsigned short*)(ws + (typ ? OFF_PKT : OFF_PKS)) + (size_t)c * NN * DD;
  float* qarr = (float*)(ws + (typ ? OFF_QBFT : OFF_QBFS)) + c * NN;
  float* wtp  = (float*)(ws + OFF_WTP) + c * NN;
  float vax = 0.f, vay = 0.f, vaz = 0.f, vaw = 0.f, sqa = 0.f;
  int mstart = chunk * 4 + wv;
  for (int m0 = mstart; m0 < count; m0 += 256) {
    int mm[4]; bool act[4]; float4 v[4];
#pragma unroll
    for (int b = 0; b < 4; ++b) {
      int m = m0 + b * 64;
      act[b] = (m < count);
      mm[b] = act[b] ? m : m0;
    }
#pragma unroll
    for (int b = 0; b < 4; ++b) {
      int idx = ls_idx[mm[b]];
      v[b] = *(const float4*)&feats[(size_t)idx * DD + lane * 4];
    }
#pragma unroll
    for (int b = 0; b < 4; ++b) {
      float raw = wred64(v[b].x * v[b].x + v[b].y * v[b].y
                       + v[b].z * v[b].z + v[b].w * v[b].w);
      unsigned ux = __float_as_uint(v[b].x); ux = (ux + 0x7fffu + ((ux >> 16) & 1u)) & 0xffff0000u;
      unsigned uy = __float_as_uint(v[b].y); uy = (uy + 0x7fffu + ((uy >> 16) & 1u)) & 0xffff0000u;
      unsigned uz = __float_as_uint(v[b].z); uz = (uz + 0x7fffu + ((uz >> 16) & 1u)) & 0xffff0000u;
      unsigned uw = __float_as_uint(v[b].w); uw = (uw + 0x7fffu + ((uw >> 16) & 1u)) & 0xffff0000u;
      float rx = __uint_as_float(ux), ry = __uint_as_float(uy);
      float rz = __uint_as_float(uz), rw = __uint_as_float(uw);
      float rq = wred64(rx * rx + ry * ry + rz * rz + rw * rw);
      if (act[b]) {
        vax += v[b].x; vay += v[b].y; vaz += v[b].z; vaw += v[b].w;
        sqa += raw;
        ushort4 b4;
        b4.x = (unsigned short)(ux >> 16); b4.y = (unsigned short)(uy >> 16);
        b4.z = (unsigned short)(uz >> 16); b4.w = (unsigned short)(uw >> 16);
        *(ushort4*)&pk[(size_t)mm[b] * DD + lane * 4] = b4;
        if (lane == 0) {
          qarr[mm[b]] = rq;
          if (typ) wtp[mm[b]] = ls_wt[mm[b]];
        }
      }
    }
  }
  ls_mom[wv][lane * 4 + 0] = vax; ls_mom[wv][lane * 4 + 1] = vay;
  ls_mom[wv][lane * 4 + 2] = vaz; ls_mom[wv][lane * 4 + 3] = vaw;
  if (lane == 0) ls_sq[wv] = sqa;
  __syncthreads();
  float s = ls_mom[0][tid] + ls_mom[1][tid] + ls_mom[2][tid] + ls_mom[3][tid];
  float* vp = (float*)(ws + (typ ? OFF_VTP : OFF_VSP)) + (c * 16 + chunk) * 256;
  vp[tid] = s;
  if (tid == 0)
    ((float*)(ws + (typ ? OFF_SQTP : OFF_SQSP)))[c * 16 + chunk] =
        ls_sq[0] + ls_sq[1] + ls_sq[2] + ls_sq[3];
}

// ---------------- KB: 193 blocks = type(3) x class(8) x rtile(8) + finale ----------------
__global__ __launch_bounds__(256) void ecda_pairs(
    const float* __restrict__ cw, char* __restrict__ ws,
    float* __restrict__ out) {
  __shared__ float shred[4];
  __shared__ float sh4[4];
  __shared__ float shb[8];      // 0:dss 1:dtt 2:dst 3:sqs 4:sqt
  __shared__ float shs[6];      // scale, ib0..ib4
  __shared__ float sh_vt[8][256];
  __shared__ float sh_coef[8], sh_ccomp[8];
  __shared__ float dcen[28];
  int tid = threadIdx.x, bx = blockIdx.x;
  int wv = tid >> 6, lane = tid & 63;
  const int* cnt_s = (const int*)(ws + OFF_CNT_S);
  const int* cnt_t = (const int*)(ws + OFF_CNT_T);
  const float* vsp = (const float*)(ws + OFF_VSP);
  const float* vtp = (const float*)(ws + OFF_VTP);
  const float* sqsp = (const float*)(ws + OFF_SQSP);
  const float* sqtp = (const float*)(ws + OFF_SQTP);

  if (bx == 192) {                         // finale: repulsion + compact + base
    float meanw = 0.f;
    for (int c2 = 0; c2 < NC; ++c2) meanw += cw[c2];
    meanw *= (1.f / NC);
    for (int cc = wv; cc < 8; cc += 4) {   // each wave handles 2 classes
      f32x4 vtd = {0.f, 0.f, 0.f, 0.f};
#pragma unroll
      for (int ch = 0; ch < 16; ++ch)
        vtd += *(const f32x4*)&vtp[(cc * 16 + ch) * 256 + lane * 4];
      *(f32x4*)&sh_vt[cc][lane * 4] = vtd;
      float dtt = wred64(vtd[0]*vtd[0] + vtd[1]*vtd[1] + vtd[2]*vtd[2] + vtd[3]*vtd[3]);
      float sqt = wred64((lane < 16) ? sqtp[cc * 16 + lane] : 0.f);
      if (lane == 0) {
        int nsi = cnt_s[cc], nti = cnt_t[cc];
        float nt = (float)nti;
        float coef = (nsi >= 2 && nti >= 2) ? expf(meanw - cw[cc]) : 0.f;
        float mx = fmaxf(nt, 1.f);
        float compact = (sqt - 2.f * dtt / mx + nt * dtt / (mx * mx)) / mx;
        sh_coef[cc] = coef;
        sh_ccomp[cc] = coef * 0.1f * compact;
      }
    }
    __syncthreads();
    for (int t = wv; t < 28; t += 4) {
      int a = 0, r = t;
      while (r >= 7 - a) { r -= 7 - a; ++a; }
      int b = a + 1 + r;
      float ima = 1.f / fmaxf((float)cnt_t[a], 1.f);
      float imb = 1.f / fmaxf((float)cnt_t[b], 1.f);
      float4 x = *(const float4*)&sh_vt[a][lane * 4];
      float4 y = *(const float4*)&sh_vt[b][lane * 4];
      float dx = x.x * ima - y.x * imb, dy = x.y * ima - y.y * imb;
      float dz = x.z * ima - y.z * imb, dw = x.w * ima - y.w * imb;
      float ssum = wred64(dx * dx + dy * dy + dz * dz + dw * dw);
      if (lane == 0) dcen[t] = sqrtf(fmaxf(ssum, 1e-12f));
    }
    __syncthreads();
    if (tid == 0) {
      int nvalid = 0;
      for (int c2 = 0; c2 < NC; ++c2) nvalid += (cnt_t[c2] > 0);
      float sumD = 0.f; int np = 0; int p = 0;
      for (int a = 0; a < NC; ++a)
        for (int b = a + 1; b < NC; ++b) {
          if (cnt_t[a] > 0 && cnt_t[b] > 0) { sumD += dcen[p]; ++np; }
          ++p;
        }
      float repl = (nvalid > 1) ? (-sumD / fmaxf((float)np, 1.f)) : 0.f;
      float base2 = 0.f, csum = 0.f;
      for (int c2 = 0; c2 < NC; ++c2) { base2 += sh_ccomp[c2]; csum += sh_coef[c2]; }
      base2 += 0.01f * repl * csum;
      atomicAdd(out, base2);
    }
    return;
  }

  // -------- stripe block: one (type, class, rtile), loop over ctiles --------
  int type  = bx >> 6;
  int c     = (bx >> 3) & 7;
  int rtile = bx & 7;

  int nsc = cnt_s[c], ntc = cnt_t[c];
  if (nsc < 2 || ntc < 2) return;          // gated class (coef == 0)
  int na = (type == 1) ? ntc : nsc;
  int nb = (type == 0) ? nsc : ntc;
  int rbase = rtile * 32;
  if (rbase >= na) return;
  int ct0 = (type <= 1) ? rtile : 0;       // symmetric: upper triangle only
  int nbt = (nb + 31) >> 5;
  if (ct0 >= nbt) return;

  const unsigned short* pkS = (const unsigned short*)(ws + OFF_PKS) + (size_t)c * NN * DD;
  const unsigned short* pkT = (const unsigned short*)(ws + OFF_PKT) + (size_t)c * NN * DD;
  const float* qbS = (const float*)(ws + OFF_QBFS) + c * NN;
  const float* qbT = (const float*)(ws + OFF_QBFT) + c * NN;
  const float* wtp = (const float*)(ws + OFF_WTP) + c * NN;
  const unsigned short* pkA = (type == 1) ? pkT : pkS;
  const unsigned short* pkB = (type == 0) ? pkS : pkT;
  const float* qaB = (type == 1) ? qbT : qbS;
  const float* qbB = (type == 0) ? qbS : qbT;

  // A-side (fixed for the whole stripe): issue loads early
  int sr = (wv >> 1) * 16, sc2 = (wv & 1) * 16;
  int posA = rbase + sr + (lane & 15);
  int pAc = posA < na ? posA : (na - 1);
  const unsigned short* rowA = pkA + (size_t)pAc * DD + (lane >> 4) * 8;
  bf16x8 afr[8];
#pragma unroll
  for (int ks = 0; ks < 8; ++ks) afr[ks] = *(const bf16x8*)(rowA + ks * 32);
  int rowbase = rbase + sr + ((lane >> 4) << 2);          // multiple of 4
  f32x4 qA4 = *(const f32x4*)&qaB[rowbase];               // poison past count is gated
  f32x4 wA4 = {1.f, 1.f, 1.f, 1.f};
  if (type == 1) wA4 = *(const f32x4*)&wtp[rowbase];

  // redundant per-class scalar prologue from chunk partials (reads only)
  {
    float vsd = 0.f, vtd = 0.f;
#pragma unroll
    for (int ch = 0; ch < 16; ++ch) {
      vsd += vsp[(c * 16 + ch) * 256 + tid];
      vtd += vtp[(c * 16 + ch) * 256 + tid];
    }
    if (wv == 2) {
      float s = wred64((lane < 16) ? sqsp[c * 16 + lane] : 0.f);
      if (lane == 0) shb[3] = s;
    }
    if (wv == 3) {
      float s = wred64((lane < 16) ? sqtp[c * 16 + lane] : 0.f);
      if (lane == 0) shb[4] = s;
    }
    float r1 = brs256(vsd * vsd, sh4); if (tid == 0) shb[0] = r1;
    float r2 = brs256(vtd * vtd, sh4); if (tid == 0) shb[1] = r2;
    float r3 = brs256(vsd * vtd, sh4); if (tid == 0) shb[2] = r3;
    __syncthreads();
    if (tid == 0) {
      float ns = (float)nsc, nt = (float)ntc, n = ns + nt;
      float sumL2 = 2.f * ns * shb[3] - 2.f * shb[0]
                  + 2.f * nt * shb[4] - 2.f * shb[1]
                  + 2.f * (nt * shb[3] + ns * shb[4] - 2.f * shb[2]);
      float bw0 = sumL2 / fmaxf(n * n - n, 1.f) * 0.25f;  // /half, half=4
      float mul = 1.f;
      for (int k = 0; k < 5; ++k) { shs[1 + k] = 1.f / (bw0 * mul + 1e-8f); mul *= 2.f; }
      float meanw = 0.f;
      for (int c2 = 0; c2 < NC; ++c2) meanw += cw[c2];
      meanw *= (1.f / NC);
      float attn = expf(meanw - cw[c]);                    // LAMBDA = 1
      float swc = ((const float*)(ws + OFF_SW))[c];
      float scale = (type == 0) ? attn / (ns * ns + 1e-8f)
                  : (type == 1) ? attn / (swc * swc + 1e-8f)
                                : -2.f * attn / (ns * swc + 1e-8f);
      shs[0] = scale;
    }
    __syncthreads();
  }
  float ib0 = shs[1], ib1 = shs[2], ib2 = shs[3], ib3 = shs[4], ib4 = shs[5];

  // ctile loop: B-frags + MFMA + epilogue; per-lane accumulate across tiles
  float lacc = 0.f;
  for (int ctile = ct0; ctile < nbt; ++ctile) {
    int cbase = ctile * 32;
    int posB = cbase + sc2 + (lane & 15);
    int pBc = posB < nb ? posB : (nb - 1);
    const unsigned short* rowB = pkB + (size_t)pBc * DD + (lane >> 4) * 8;
    f32x4 acc = {0.f, 0.f, 0.f, 0.f};
#pragma unroll
    for (int ks = 0; ks < 8; ++ks) {
      bf16x8 bf = *(const bf16x8*)(rowB + ks * 32);
      acc = __builtin_amdgcn_mfma_f32_16x16x32_bf16(afr[ks], bf, acc, 0, 0, 0);
    }
    bool jval = (posB < nb);
    float knj = qbB[pBc];
    float wj = (type == 0) ? 1.f : wtp[pBc];
    float factor = (type <= 1 && ctile > rtile) ? 2.f : 1.f;
    float partial = 0.f;
#pragma unroll
    for (int r = 0; r < 4; ++r) {
      int ip = rowbase + r;
      bool val = jval && (ip < na);
      float d2 = fmaxf(qA4[r] + knj - 2.f * acc[r], 0.f);
      float e = __expf(-d2 * ib0) + __expf(-d2 * ib1) + __expf(-d2 * ib2)
              + __expf(-d2 * ib3) + __expf(-d2 * ib4);
      float wgt = (type == 1) ? wA4[r] * wj : wj;
      partial += val ? wgt * e : 0.f;
    }
    lacc += factor * partial;
  }
  lacc = wred64(lacc);
  if (lane == 0) shred[wv] = lacc;
  __syncthreads();
  if (tid == 0) {
    float tot = shred[0] + shred[1] + shred[2] + shred[3];
    atomicAdd(out, shs[0] * tot);
  }
}

extern "C" void kernel_launch(void* const* d_in, const int* in_sizes, int n_in,
                              void* d_out, int out_size, void* d_ws, size_t ws_size,
                              hipStream_t stream) {
  const float* cfeat  = (const float*)d_in[0];
  const float* nfeat  = (const float*)d_in[1];
  const int*   clab   = (const int*)d_in[2];
  const int*   nlab   = (const int*)d_in[3];
  const float* nmask  = (const float*)d_in[4];
  const float* nscore = (const float*)d_in[5];
  const float* cw     = (const float*)d_in[6];
  float* out = (float*)d_out;
  char* ws = (char*)d_ws;

  ecda_pack<<<256, 256, 0, stream>>>(cfeat, nfeat, clab, nlab, nmask, nscore,
                                     ws, out);
  ecda_pairs<<<193, 256, 0, stream>>>(cw, ws, out);
}

// Round 11
// 27.652 us; speedup vs baseline: 2.0781x; 1.1841x over previous
//
#include <hip/hip_runtime.h>
#include <math.h>

// ECDA loss, 3-kernel formulation, latency-optimized.
// KA ecda_pack (256 blocks): pack class rows into compacted bf16 matrices +
//   bf16-norms + weights + chunk-partial moments/raw-norm-sums.
// K2 ecda_scalars (8 blocks): reduce partials -> per-class scalars, 32B
//   headers, reduced vt, coef/ccomp.
// KB ecda_pairs (385 blocks): 384 half-stripe MFMA blocks (header-only
//   prologue, column-parity split) + finale block (repulsion + base).

static constexpr int NC = 8;
static constexpr int NN = 2048;
static constexpr int DD = 256;

// workspace byte offsets
static constexpr int OFF_CNT_S = 0;         // 8 int
static constexpr int OFF_CNT_T = 64;        // 8 int
static constexpr int OFF_SW    = 128;       // 8 f32
static constexpr int OFF_COEF  = 192;       // 8 f32 (attn coef, gated)
static constexpr int OFF_CCOMP = 256;       // 8 f32 (coef*0.1*compact)
static constexpr int OFF_SQSP  = 1024;      // 8*16 f32 partial raw-norm sums (clean)
static constexpr int OFF_SQTP  = 1536;      // 8*16 f32 (noisy)
static constexpr int OFF_HDR   = 2048;      // 24*8 f32 headers [type*8+c]: na,nb,scale,ib0..ib4
static constexpr int OFF_VSP   = 4096;      // 8c*16ch*256 f32 partial moments (clean)
static constexpr int OFF_VTP   = 135168;    // same (noisy)
static constexpr int OFF_VS    = 266240;    // 8*256 f32 reduced
static constexpr int OFF_VT    = 274432;    // 8*256 f32
static constexpr int OFF_QBFS  = 282624;    // 8*2048 f32 bf16-norms by position (clean)
static constexpr int OFF_QBFT  = 348160;    // 8*2048 f32 (noisy)
static constexpr int OFF_WTP   = 413696;    // 8*2048 f32 weights by position
static constexpr size_t OFF_PKS = 479232;   // 8*2048*256 bf16 packed clean (8 MB)
static constexpr size_t OFF_PKT = 8867840;  // packed noisy (8 MB)
// total ~17.3 MB

typedef __attribute__((ext_vector_type(8))) short bf16x8;
typedef __attribute__((ext_vector_type(4))) float f32x4;

__device__ inline float wred64(float v) {
  for (int o = 32; o > 0; o >>= 1) v += __shfl_xor(v, o, 64);
  return v;
}
__device__ inline float brs256(float v, float* sh4) {
  for (int o = 32; o > 0; o >>= 1) v += __shfl_xor(v, o, 64);
  int w = threadIdx.x >> 6, ln = threadIdx.x & 63;
  __syncthreads();
  if (ln == 0) sh4[w] = v;
  __syncthreads();
  float r = 0.f;
  if (threadIdx.x == 0) r = sh4[0] + sh4[1] + sh4[2] + sh4[3];
  return r;
}

// ---------------- KA: 256 blocks = typ(2) x class(8) x chunk(16) ----------------
__global__ __launch_bounds__(256) void ecda_pack(
    const float* __restrict__ cfeat, const float* __restrict__ nfeat,
    const int* __restrict__ clab, const int* __restrict__ nlab,
    const float* __restrict__ nmask, const float* __restrict__ nscore,
    char* __restrict__ ws, float* __restrict__ out) {
  __shared__ int   ls_idx[NN];
  __shared__ float ls_wt[NN];
  __shared__ int   ls_cntw[4];
  __shared__ float ls_mom[4][256];
  __shared__ float ls_sq[4];
  __shared__ float sh4[4];
  int tid = threadIdx.x, bx = blockIdx.x;
  int wv = tid >> 6, lane = tid & 63;
  int typ = bx >> 7, c = (bx >> 4) & 7, chunk = bx & 15;

  if (bx == 0 && tid == 0) out[0] = 0.f;

  const int* labs = typ ? nlab : clab;
  const float* feats = typ ? nfeat : cfeat;

  // pass 1: per-wave match masks over its 512 rows
  int rb = wv * 512;
  int lv[8]; float mv[8], sv[8];
#pragma unroll
  for (int it = 0; it < 8; ++it) {
    int i = rb + it * 64 + lane;
    lv[it] = labs[i];
    if (typ) { mv[it] = nmask[i]; sv[it] = nscore[i]; }
  }
  unsigned long long msks[8];
  int cntw = 0;
#pragma unroll
  for (int it = 0; it < 8; ++it) {
    bool m = (lv[it] == c) && (!typ || mv[it] > 0.5f);
    msks[it] = __ballot(m);
    cntw += __popcll(msks[it]);
  }
  if (lane == 0) ls_cntw[wv] = cntw;
  __syncthreads();
  int base = 0;
  for (int w2 = 0; w2 < wv; ++w2) base += ls_cntw[w2];
  // pass 2: write compacted list (+weights)
#pragma unroll
  for (int it = 0; it < 8; ++it) {
    bool m = (msks[it] >> lane) & 1ull;
    int pos = __popcll(msks[it] & ((1ull << lane) - 1ull));
    if (m) {
      ls_idx[base + pos] = rb + it * 64 + lane;
      ls_wt[base + pos] = typ ? sv[it] : 1.f;
    }
    base += __popcll(msks[it]);
  }
  __syncthreads();
  int count = ls_cntw[0] + ls_cntw[1] + ls_cntw[2] + ls_cntw[3];

  if (chunk == 0) {
    if (tid == 0) (typ ? (int*)(ws + OFF_CNT_T) : (int*)(ws + OFF_CNT_S))[c] = count;
    if (typ) {
      float s = 0.f;
      for (int i = tid; i < count; i += 256) s += ls_wt[i];
      s = brs256(s, sh4);
      if (tid == 0) ((float*)(ws + OFF_SW))[c] = s;
    }
  }

  // pack rows; per-wave m-stream = chunk*4 + wv (stride 256), 4-row batches.
  // raw-norm accumulated PER LANE (one wred64 per wave at end, not per row).
  unsigned short* pk = (unsigned short*)(ws + (typ ? OFF_PKT : OFF_PKS)) + (size_t)c * NN * DD;
  float* qarr = (float*)(ws + (typ ? OFF_QBFT : OFF_QBFS)) + c * NN;
  float* wtp  = (float*)(ws + OFF_WTP) + c * NN;
  float vax = 0.f, vay = 0.f, vaz = 0.f, vaw = 0.f, qlane = 0.f;
  int mstart = chunk * 4 + wv;
  for (int m0 = mstart; m0 < count; m0 += 256) {
    int mm[4]; bool act[4]; float4 v[4];
#pragma unroll
    for (int b = 0; b < 4; ++b) {
      int m = m0 + b * 64;
      act[b] = (m < count);
      mm[b] = act[b] ? m : m0;
    }
#pragma unroll
    for (int b = 0; b < 4; ++b) {
      int idx = ls_idx[mm[b]];
      v[b] = *(const float4*)&feats[(size_t)idx * DD + lane * 4];
    }
#pragma unroll
    for (int b = 0; b < 4; ++b) {
      unsigned ux = __float_as_uint(v[b].x); ux = (ux + 0x7fffu + ((ux >> 16) & 1u)) & 0xffff0000u;
      unsigned uy = __float_as_uint(v[b].y); uy = (uy + 0x7fffu + ((uy >> 16) & 1u)) & 0xffff0000u;
      unsigned uz = __float_as_uint(v[b].z); uz = (uz + 0x7fffu + ((uz >> 16) & 1u)) & 0xffff0000u;
      unsigned uw = __float_as_uint(v[b].w); uw = (uw + 0x7fffu + ((uw >> 16) & 1u)) & 0xffff0000u;
      float rx = __uint_as_float(ux), ry = __uint_as_float(uy);
      float rz = __uint_as_float(uz), rw = __uint_as_float(uw);
      float rq = wred64(rx * rx + ry * ry + rz * rz + rw * rw);
      if (act[b]) {
        vax += v[b].x; vay += v[b].y; vaz += v[b].z; vaw += v[b].w;
        qlane += v[b].x * v[b].x + v[b].y * v[b].y + v[b].z * v[b].z + v[b].w * v[b].w;
        ushort4 b4;
        b4.x = (unsigned short)(ux >> 16); b4.y = (unsigned short)(uy >> 16);
        b4.z = (unsigned short)(uz >> 16); b4.w = (unsigned short)(uw >> 16);
        *(ushort4*)&pk[(size_t)mm[b] * DD + lane * 4] = b4;
        if (lane == 0) {
          qarr[mm[b]] = rq;
          if (typ) wtp[mm[b]] = ls_wt[mm[b]];
        }
      }
    }
  }
  float sqa = wred64(qlane);
  ls_mom[wv][lane * 4 + 0] = vax; ls_mom[wv][lane * 4 + 1] = vay;
  ls_mom[wv][lane * 4 + 2] = vaz; ls_mom[wv][lane * 4 + 3] = vaw;
  if (lane == 0) ls_sq[wv] = sqa;
  __syncthreads();
  float s = ls_mom[0][tid] + ls_mom[1][tid] + ls_mom[2][tid] + ls_mom[3][tid];
  float* vp = (float*)(ws + (typ ? OFF_VTP : OFF_VSP)) + (c * 16 + chunk) * 256;
  vp[tid] = s;
  if (tid == 0)
    ((float*)(ws + (typ ? OFF_SQTP : OFF_SQSP)))[c * 16 + chunk] =
        ls_sq[0] + ls_sq[1] + ls_sq[2] + ls_sq[3];
}

// ---------------- K2: 8 blocks, one class each ----------------
__global__ __launch_bounds__(256) void ecda_scalars(
    const float* __restrict__ cw, char* __restrict__ ws) {
  __shared__ float sh4[4];
  int c = blockIdx.x, tid = threadIdx.x;
  const float* vsp = (const float*)(ws + OFF_VSP);
  const float* vtp = (const float*)(ws + OFF_VTP);
  float vsd = 0.f, vtd = 0.f;
#pragma unroll
  for (int ch = 0; ch < 16; ++ch) {
    vsd += vsp[(c * 16 + ch) * 256 + tid];
    vtd += vtp[(c * 16 + ch) * 256 + tid];
  }
  ((float*)(ws + OFF_VS))[c * 256 + tid] = vsd;
  ((float*)(ws + OFF_VT))[c * 256 + tid] = vtd;
  float dss = brs256(vsd * vsd, sh4);
  float dtt = brs256(vtd * vtd, sh4);
  float dst = brs256(vsd * vtd, sh4);
  if (tid == 0) {
    const float* sqsp = (const float*)(ws + OFF_SQSP);
    const float* sqtp = (const float*)(ws + OFF_SQTP);
    float sqs = 0.f, sqt = 0.f;
    for (int ch = 0; ch < 16; ++ch) { sqs += sqsp[c * 16 + ch]; sqt += sqtp[c * 16 + ch]; }
    int nsi = ((const int*)(ws + OFF_CNT_S))[c];
    int nti = ((const int*)(ws + OFF_CNT_T))[c];
    float ns = (float)nsi, nt = (float)nti, n = ns + nt;
    float sumL2 = 2.f * ns * sqs - 2.f * dss
                + 2.f * nt * sqt - 2.f * dtt
                + 2.f * (nt * sqs + ns * sqt - 2.f * dst);
    float bw0 = sumL2 / fmaxf(n * n - n, 1.f) * 0.25f;    // /half, half=4
    float ib[5];
    float mul = 1.f;
    for (int k = 0; k < 5; ++k) { ib[k] = 1.f / (bw0 * mul + 1e-8f); mul *= 2.f; }
    float meanw = 0.f;
    for (int c2 = 0; c2 < NC; ++c2) meanw += cw[c2];
    meanw *= (1.f / NC);
    float attn = expf(meanw - cw[c]);                     // LAMBDA = 1
    float coef = (nsi >= 2 && nti >= 2) ? attn : 0.f;
    float swc = ((const float*)(ws + OFF_SW))[c];
    float scc = coef / (ns * ns + 1e-8f);
    float snn = coef / (swc * swc + 1e-8f);
    float scn = -2.f * coef / (ns * swc + 1e-8f);
    // headers: [type*8+c]*8 floats = {na, nb, scale, ib0, ib1, ib2, ib3, ib4}
    float* hdr = (float*)(ws + OFF_HDR);
    for (int ty = 0; ty < 3; ++ty) {
      float* h = hdr + (ty * 8 + c) * 8;
      int na = (ty == 1) ? nti : nsi;
      int nb = (ty == 0) ? nsi : nti;
      h[0] = __int_as_float(na);
      h[1] = __int_as_float(nb);
      h[2] = (ty == 0) ? scc : (ty == 1) ? snn : scn;
      h[3] = ib[0]; h[4] = ib[1]; h[5] = ib[2]; h[6] = ib[3]; h[7] = ib[4];
    }
    float mx = fmaxf(nt, 1.f);
    float compact = (sqt - 2.f * dtt / mx + nt * dtt / (mx * mx)) / mx;
    ((float*)(ws + OFF_COEF))[c] = coef;
    ((float*)(ws + OFF_CCOMP))[c] = coef * 0.1f * compact;
  }
}

// ---------------- KB: 385 blocks = type(3)x class(8)x rtile(8)x par(2) + finale ----------------
__global__ __launch_bounds__(256) void ecda_pairs(
    const float* __restrict__ cw, char* __restrict__ ws,
    float* __restrict__ out) {
  __shared__ float shred[4];
  __shared__ float dcen[28];
  int tid = threadIdx.x, bx = blockIdx.x;
  int wv = tid >> 6, lane = tid & 63;

  if (bx == 384) {                         // finale: repulsion + base
    const int* cnt_t = (const int*)(ws + OFF_CNT_T);
    const float* vt = (const float*)(ws + OFF_VT);
    for (int t = wv; t < 28; t += 4) {
      int a = 0, r = t;
      while (r >= 7 - a) { r -= 7 - a; ++a; }
      int b = a + 1 + r;
      float ima = 1.f / fmaxf((float)cnt_t[a], 1.f);
      float imb = 1.f / fmaxf((float)cnt_t[b], 1.f);
      float4 x = *(const float4*)&vt[a * DD + lane * 4];
      float4 y = *(const float4*)&vt[b * DD + lane * 4];
      float dx = x.x * ima - y.x * imb, dy = x.y * ima - y.y * imb;
      float dz = x.z * ima - y.z * imb, dw = x.w * ima - y.w * imb;
      float ssum = wred64(dx * dx + dy * dy + dz * dz + dw * dw);
      if (lane == 0) dcen[t] = sqrtf(fmaxf(ssum, 1e-12f));
    }
    __syncthreads();
    if (tid == 0) {
      int nvalid = 0;
      for (int c2 = 0; c2 < NC; ++c2) nvalid += (cnt_t[c2] > 0);
      float sumD = 0.f; int np = 0; int p = 0;
      for (int a = 0; a < NC; ++a)
        for (int b = a + 1; b < NC; ++b) {
          if (cnt_t[a] > 0 && cnt_t[b] > 0) { sumD += dcen[p]; ++np; }
          ++p;
        }
      float repl = (nvalid > 1) ? (-sumD / fmaxf((float)np, 1.f)) : 0.f;
      const float* coefA = (const float*)(ws + OFF_COEF);
      const float* ccomp = (const float*)(ws + OFF_CCOMP);
      float base2 = 0.f, csum = 0.f;
      for (int c2 = 0; c2 < NC; ++c2) { base2 += ccomp[c2]; csum += coefA[c2]; }
      base2 += 0.01f * repl * csum;
      atomicAdd(out, base2);
    }
    return;
  }

  // -------- half-stripe block: (type, class, rtile, parity) --------
  int par   = bx & 1;
  int rtile = (bx >> 1) & 7;
  int c     = (bx >> 4) & 7;
  int type  = bx >> 7;

  const f32x4* H = (const f32x4*)((const char*)ws + OFF_HDR) + (type * 8 + c) * 2;
  f32x4 h0 = H[0];
  int na = __float_as_int(h0[0]);
  int nb = __float_as_int(h0[1]);
  float scale = h0[2];
  int rbase = rtile * 32;
  if (scale == 0.f || rbase >= na || nb <= 0) return;
  int ct0 = (type <= 1) ? rtile : 0;       // symmetric: upper triangle only
  int nbt = (nb + 31) >> 5;
  if (ct0 + par >= nbt) return;
  f32x4 h1 = H[1];
  float ib0 = h0[3], ib1 = h1[0], ib2 = h1[1], ib3 = h1[2], ib4 = h1[3];

  const unsigned short* pkS = (const unsigned short*)(ws + OFF_PKS) + (size_t)c * NN * DD;
  const unsigned short* pkT = (const unsigned short*)(ws + OFF_PKT) + (size_t)c * NN * DD;
  const float* qbS = (const float*)(ws + OFF_QBFS) + c * NN;
  const float* qbT = (const float*)(ws + OFF_QBFT) + c * NN;
  const float* wtp = (const float*)(ws + OFF_WTP) + c * NN;
  const unsigned short* pkA = (type == 1) ? pkT : pkS;
  const unsigned short* pkB = (type == 0) ? pkS : pkT;
  const float* qaB = (type == 1) ? qbT : qbS;
  const float* qbB = (type == 0) ? qbS : qbT;

  // A-side (fixed for the whole stripe): issue loads once
  int sr = (wv >> 1) * 16, sc2 = (wv & 1) * 16;
  int posA = rbase + sr + (lane & 15);
  int pAc = posA < na ? posA : (na - 1);
  const unsigned short* rowA = pkA + (size_t)pAc * DD + (lane >> 4) * 8;
  bf16x8 afr[8];
#pragma unroll
  for (int ks = 0; ks < 8; ++ks) afr[ks] = *(const bf16x8*)(rowA + ks * 32);
  int rowbase = rbase + sr + ((lane >> 4) << 2);          // multiple of 4
  f32x4 qA4 = *(const f32x4*)&qaB[rowbase];               // poison past count is gated
  f32x4 wA4 = {1.f, 1.f, 1.f, 1.f};
  if (type == 1) wA4 = *(const f32x4*)&wtp[rowbase];

  // ctile loop (parity-strided): B-frags + MFMA + epilogue
  float lacc = 0.f;
  for (int ctile = ct0 + par; ctile < nbt; ctile += 2) {
    int cbase = ctile * 32;
    int posB = cbase + sc2 + (lane & 15);
    int pBc = posB < nb ? posB : (nb - 1);
    const unsigned short* rowB = pkB + (size_t)pBc * DD + (lane >> 4) * 8;
    f32x4 acc = {0.f, 0.f, 0.f, 0.f};
#pragma unroll
    for (int ks = 0; ks < 8; ++ks) {
      bf16x8 bf = *(const bf16x8*)(rowB + ks * 32);
      acc = __builtin_amdgcn_mfma_f32_16x16x32_bf16(afr[ks], bf, acc, 0, 0, 0);
    }
    bool jval = (posB < nb);
    float knj = qbB[pBc];
    float wj = (type == 0) ? 1.f : wtp[pBc];
    float factor = (type <= 1 && ctile > rtile) ? 2.f : 1.f;
    float partial = 0.f;
#pragma unroll
    for (int r = 0; r < 4; ++r) {
      int ip = rowbase + r;
      bool val = jval && (ip < na);
      float d2 = fmaxf(qA4[r] + knj - 2.f * acc[r], 0.f);
      float e = __expf(-d2 * ib0) + __expf(-d2 * ib1) + __expf(-d2 * ib2)
              + __expf(-d2 * ib3) + __expf(-d2 * ib4);
      float wgt = (type == 1) ? wA4[r] * wj : wj;
      partial += val ? wgt * e : 0.f;
    }
    lacc += factor * partial;
  }
  lacc = wred64(lacc);
  if (lane == 0) shred[wv] = lacc;
  __syncthreads();
  if (tid == 0) {
    float tot = shred[0] + shred[1] + shred[2] + shred[3];
    if (tot != 0.f) atomicAdd(out, scale * tot);
  }
}

extern "C" void kernel_launch(void* const* d_in, const int* in_sizes, int n_in,
                              void* d_out, int out_size, void* d_ws, size_t ws_size,
                              hipStream_t stream) {
  const float* cfeat  = (const float*)d_in[0];
  const float* nfeat  = (const float*)d_in[1];
  const int*   clab   = (const int*)d_in[2];
  const int*   nlab   = (const int*)d_in[3];
  const float* nmask  = (const float*)d_in[4];
  const float* nscore = (const float*)d_in[5];
  const float* cw     = (const float*)d_in[6];
  float* out = (float*)d_out;
  char* ws = (char*)d_ws;

  ecda_pack<<<256, 256, 0, stream>>>(cfeat, nfeat, clab, nlab, nmask, nscore,
                                     ws, out);
  ecda_scalars<<<8, 256, 0, stream>>>(cw, ws);
  ecda_pairs<<<385, 256, 0, stream>>>(cw, ws, out);
}